// Round 9
// baseline (45.010 us; speedup 1.0000x reference)
//
#include <hip/hip_runtime.h>

#define BB 128
#define TT 512
#define NBLK 1024        // 128 rows x 8 lag-chunks
#define L1GRP 16         // blocks per level-1 group
#define NL1 (NBLK / L1GRP)   // 64 groups
#define CSTRIDE 32       // uints between counters = 128 B (own cacheline)
#define LAG_PENALTY 0.5f

// Single-node fused kernel with a 2-level residue-ticket reduction tree.
// Winner rule old % k == k-1 is poison/replay-safe: each counter receives
// exactly k increments per call (complete residue system mod k, k | 2^32),
// so exactly one winner per level per call for ANY initial counter value.
// Publishes via atomicExch + threadfence; reads via atomicAdd(p,0) at the
// coherence point (immune to per-XCD L2 staleness). Fixed summation order
// -> bit-identical output whichever blocks win. No spin, no flat 1024-deep
// same-address serialization (R8's 14 us mistake).

__global__ __launch_bounds__(512, 4) void WeightedLagDenseLoss_fused(
    const float* __restrict__ pred,
    const float* __restrict__ tgt,
    const float* __restrict__ wts,
    float* __restrict__ part,            // d_ws: NBLK floats
    float* __restrict__ gsum,            // NL1 floats
    unsigned int* __restrict__ c1,       // NL1 counters, CSTRIDE apart
    unsigned int* __restrict__ cg,       // 1 global counter
    float* __restrict__ out)
{
    __shared__ float4 s_ext4[256];   // 1024 floats: row [0..511], g511-pad
    __shared__ float  s_part[8];
    float* s_ext = reinterpret_cast<float*>(s_ext4);

    const int bid = blockIdx.x;
    const int row = bid >> 3;        // 0..127
    const int s   = bid & 7;         // lag chunk: lags [64s, 64s+64)
    const int tid = threadIdx.x;
    const int j   = tid & 127;       // t-group: t = 4j..4j+3
    const int q   = tid >> 7;        // lag subchunk: lags [64s+16q, +16)

    // Stage extended target row (clamp-pad with g[511])
    const float g511 = tgt[row * TT + TT - 1];
    s_ext[tid]       = tgt[row * TT + tid];
    s_ext[TT + tid]  = g511;
    __syncthreads();

    // 1/l for this thread's 16 lags, via v_rcp (off the LDS pipe)
    const int L0 = 64 * s + 16 * q;
    float r[16];
    #pragma unroll
    for (int i = 0; i < 16; ++i) {
        const int l = L0 + i;
        r[i] = (l == 0) ? 0.0f : __builtin_amdgcn_rcpf((float)l);
    }

    const float4 p = *reinterpret_cast<const float4*>(&pred[row * TT + 4 * j]);

    // 20-float sliding window: 5 aligned ds_read_b128
    const int base4 = j + (L0 >> 2);
    float4 w4[5];
    #pragma unroll
    for (int k = 0; k < 5; ++k) w4[k] = s_ext4[base4 + k];
    const float* w = reinterpret_cast<const float*>(w4);

    float acc = 0.0f;     // sum over 16 lags x 4 t of (1/l) * d^2
    float mse = 0.0f;     // plain MSE tile (l=0 group), added once
    const bool own_mse = (s == 0) && (q == 0);

    #pragma unroll
    for (int k = 0; k < 4; ++k) {
        #pragma unroll
        for (int bb = 0; bb < 4; ++bb) {
            const int o = 4 * k + bb;
            const float d0 = p.x - w[o + 0];
            const float d1 = p.y - w[o + 1];
            const float d2 = p.z - w[o + 2];
            const float d3 = p.w - w[o + 3];
            const float sb = d0 * d0 + d1 * d1 + d2 * d2 + d3 * d3;
            acc = fmaf(r[o], sb, acc);
            if (k == 0 && bb == 0 && own_mse) mse = sb;
        }
    }

    float v = fmaf(LAG_PENALTY, acc, mse) * wts[row] * (1.0f / (float)(BB * TT));

    // block-local reduction
    for (int off = 32; off > 0; off >>= 1)
        v += __shfl_down(v, off, 64);
    if ((tid & 63) == 0) s_part[tid >> 6] = v;
    __syncthreads();

    if (tid == 0) {
        float sum = 0.0f;
        #pragma unroll
        for (int i = 0; i < 8; ++i) sum += s_part[i];

        atomicExch(&part[bid], sum);          // publish partial (device scope)
        __threadfence();                      // release
        const int g = bid >> 4;               // L1 group of 16 blocks
        unsigned int old1 = atomicAdd(&c1[g * CSTRIDE], 1u);

        if ((old1 & (L1GRP - 1)) == (L1GRP - 1)) {   // L1 winner (1 of 16)
            __threadfence();                  // acquire
            float gs = 0.0f;
            #pragma unroll
            for (int i = 0; i < L1GRP; ++i)
                gs += atomicAdd(&part[g * L1GRP + i], 0.0f);  // fresh reads
            atomicExch(&gsum[g], gs);
            __threadfence();                  // release
            unsigned int old2 = atomicAdd(cg, 1u);

            if ((old2 & (NL1 - 1)) == (NL1 - 1)) {   // global winner (1 of 64)
                __threadfence();              // acquire
                float total = 0.0f;
                #pragma unroll
                for (int i = 0; i < NL1; ++i)
                    total += atomicAdd(&gsum[i], 0.0f);
                out[0] = total;               // overwrite, no zero-init needed
            }
        }
    }
}

extern "C" void kernel_launch(void* const* d_in, const int* in_sizes, int n_in,
                              void* d_out, int out_size, void* d_ws, size_t ws_size,
                              hipStream_t stream) {
    const float* pred = (const float*)d_in[0];
    const float* tgt  = (const float*)d_in[1];
    const float* wts  = (const float*)d_in[2];
    float* out = (float*)d_out;

    // d_ws layout (base assumed >=128B aligned):
    //   [0, 1024)            part   (floats)
    //   [1024, 1088)         gsum   (floats)
    //   [1152, 1152+2048)    c1     (uints, 64 counters x CSTRIDE)
    //   next uint            cg
    float* part = (float*)d_ws;
    float* gsum = part + NBLK;
    unsigned int* c1 = (unsigned int*)(part + 1152);
    unsigned int* cg = c1 + NL1 * CSTRIDE;

    WeightedLagDenseLoss_fused<<<dim3(NBLK), dim3(TT), 0, stream>>>(
        pred, tgt, wts, part, gsum, c1, cg, out);
}

// Round 13
// 11.252 us; speedup vs baseline: 4.0003x; 4.0003x over previous
//
#include <hip/hip_runtime.h>

#define BB 128
#define TT 512
#define NPART (BB * 8)   // 1024 partials
#define LAG_PENALTY 0.5f

// PROVEN R7 structure (11.5 us, passed): two kernel nodes, no atomics, no
// cross-block ordering assumptions. Main: 1024 blocks = 128 rows x 8
// lag-chunks; register-blocked 4x4 (t,l) tiles; 20-float sliding LDS window
// = 5 aligned ds_read_b128/thread; 1/l via v_rcp; lag-0 tile doubles as the
// MSE term (weight rinv[0]=0 in the lag sum; added once by the s=0,q=0
// owner). Reduce: one 1024-thread block overwrites out[0]. All d_ws slots
// are fully overwritten every call -> poison/replay safe by construction.

__global__ __launch_bounds__(512, 4) void WeightedLagDenseLoss_main(
    const float* __restrict__ pred,
    const float* __restrict__ tgt,
    const float* __restrict__ wts,
    float* __restrict__ part)
{
    __shared__ float4 s_ext4[256];   // 1024 floats: row [0..511], g511-pad [512..1023]
    __shared__ float  s_part[8];
    float* s_ext = reinterpret_cast<float*>(s_ext4);

    const int bid = blockIdx.x;
    const int row = bid >> 3;        // 0..127
    const int s   = bid & 7;         // lag chunk: lags [64s, 64s+64)
    const int tid = threadIdx.x;
    const int j   = tid & 127;       // t-group: t = 4j..4j+3
    const int q   = tid >> 7;        // lag subchunk: lags [64s+16q, +16)

    // Stage extended target row: [0..511] = row, [512..1023] = g[511] (clamp pad)
    const float g511 = tgt[row * TT + TT - 1];   // uniform address, broadcast
    s_ext[tid]       = tgt[row * TT + tid];
    s_ext[TT + tid]  = g511;
    __syncthreads();

    // 1/l for this thread's 16 lags (l = L0 + i), v_rcp (off the LDS pipe)
    const int L0 = 64 * s + 16 * q;
    float r[16];
    #pragma unroll
    for (int i = 0; i < 16; ++i) {
        const int l = L0 + i;
        r[i] = (l == 0) ? 0.0f : __builtin_amdgcn_rcpf((float)l);
    }

    const float4 p = *reinterpret_cast<const float4*>(&pred[row * TT + 4 * j]);

    // 20-float window: float4 indices base4 .. base4+4 (max 255, exact fit)
    const int base4 = j + (L0 >> 2);
    float4 w4[5];
    #pragma unroll
    for (int k = 0; k < 5; ++k) w4[k] = s_ext4[base4 + k];
    const float* w = reinterpret_cast<const float*>(w4);

    float acc = 0.0f;     // sum over 16 lags x 4 t of (1/l) * d^2
    float mse = 0.0f;     // plain MSE for this thread's 4 t's
    const bool own_mse = (s == 0) && (q == 0);

    #pragma unroll
    for (int k = 0; k < 4; ++k) {
        #pragma unroll
        for (int bb = 0; bb < 4; ++bb) {
            const int o = 4 * k + bb;
            const float d0 = p.x - w[o + 0];
            const float d1 = p.y - w[o + 1];
            const float d2 = p.z - w[o + 2];
            const float d3 = p.w - w[o + 3];
            const float sb = d0 * d0 + d1 * d1 + d2 * d2 + d3 * d3;
            acc = fmaf(r[o], sb, acc);
            if (k == 0 && bb == 0 && own_mse) mse = sb;   // l=0 tile IS the MSE
        }
    }

    // total = (mse + 0.5*lag) * w, mean scale 1/(B*T) = 1/65536 exact
    float v = fmaf(LAG_PENALTY, acc, mse) * wts[row] * (1.0f / (float)(BB * TT));

    // wave64 shuffle reduction -> per-block partial (plain store, no atomic)
    for (int off = 32; off > 0; off >>= 1)
        v += __shfl_down(v, off, 64);

    const int wave = tid >> 6;
    if ((tid & 63) == 0) s_part[wave] = v;
    __syncthreads();

    if (tid == 0) {
        float sum = 0.0f;
        #pragma unroll
        for (int i = 0; i < 8; ++i) sum += s_part[i];
        part[bid] = sum;             // overwritten every call
    }
}

__global__ __launch_bounds__(1024) void WeightedLagDenseLoss_reduce(
    const float* __restrict__ part,
    float* __restrict__ out)
{
    __shared__ float s_part[16];
    const int t = threadIdx.x;

    float v = part[t];               // NPART == 1024 == blockDim.x

    for (int off = 32; off > 0; off >>= 1)
        v += __shfl_down(v, off, 64);

    const int wave = t >> 6;
    if ((t & 63) == 0) s_part[wave] = v;
    __syncthreads();

    if (t == 0) {
        float sum = 0.0f;
        #pragma unroll
        for (int i = 0; i < 16; ++i) sum += s_part[i];
        out[0] = sum;                // overwrite, no zero-init needed
    }
}

extern "C" void kernel_launch(void* const* d_in, const int* in_sizes, int n_in,
                              void* d_out, int out_size, void* d_ws, size_t ws_size,
                              hipStream_t stream) {
    const float* pred = (const float*)d_in[0];
    const float* tgt  = (const float*)d_in[1];
    const float* wts  = (const float*)d_in[2];
    float* out  = (float*)d_out;
    float* part = (float*)d_ws;      // 1024 floats = 4 KB scratch

    WeightedLagDenseLoss_main<<<dim3(NPART), dim3(TT), 0, stream>>>(pred, tgt, wts, part);
    WeightedLagDenseLoss_reduce<<<dim3(1), dim3(NPART), 0, stream>>>(part, out);
}

// Round 14
// 11.034 us; speedup vs baseline: 4.0794x; 1.0198x over previous
//
#include <hip/hip_runtime.h>

#define BB 128
#define TT 512
#define NPART (BB * 8)   // 1024 partials
#define LAG_PENALTY 0.5f

// Two-node structure (proven): main (1024 blocks) -> part[], reduce (1 block)
// -> out[0]. All d_ws slots fully overwritten every call; no atomics, no
// cross-block ordering assumptions -> poison/replay safe by construction.
//
// R14 change: wave-uniform clamp fast path. Thread layout j=tid>>2 (t-group),
// q=tid&3 (lag subchunk) makes min_s = 4j + L0 wave-resolvable: a wave with
// 64(w+s) >= 511 has EVERY (t,l) element clamped to g[511], so its sum
// collapses to (sum of 1/l over the window) * sum_i (p_i - g511)^2 -- ~25
// VALU + 0 LDS reads instead of ~150 VALU + 5 ds_read_b128. 28/64 of all
// (wave, chunk) instances qualify. Slow path unchanged (exact, padded
// window handles per-element clamps).

__global__ __launch_bounds__(512, 4) void WeightedLagDenseLoss_main(
    const float* __restrict__ pred,
    const float* __restrict__ tgt,
    const float* __restrict__ wts,
    float* __restrict__ part)
{
    __shared__ float4 s_ext4[256];   // 1024 floats: row [0..511], g511-pad [512..1023]
    __shared__ float  s_part[8];
    float* s_ext = reinterpret_cast<float*>(s_ext4);

    const int bid = blockIdx.x;
    const int row = bid >> 3;        // 0..127
    const int s   = bid & 7;         // lag chunk: lags [64s, 64s+64)
    const int tid = threadIdx.x;
    const int j   = tid >> 2;        // t-group: t = 4j..4j+3 (16 j's per wave)
    const int q   = tid & 3;         // lag subchunk: lags [64s+16q, +16)

    // Stage extended target row: [0..511] = row, [512..1023] = g[511] (clamp pad)
    const float g511 = tgt[row * TT + TT - 1];   // uniform address, broadcast
    s_ext[tid]       = tgt[row * TT + tid];
    s_ext[TT + tid]  = g511;
    __syncthreads();

    // 1/l for this thread's 16 lags (l = L0 + i), v_rcp (off the LDS pipe)
    const int L0 = 64 * s + 16 * q;
    float r[16];
    #pragma unroll
    for (int i = 0; i < 16; ++i) {
        const int l = L0 + i;
        r[i] = (l == 0) ? 0.0f : __builtin_amdgcn_rcpf((float)l);
    }

    const float4 p = *reinterpret_cast<const float4*>(&pred[row * TT + 4 * j]);

    float acc = 0.0f;     // sum over 16 lags x 4 t of (1/l) * d^2
    float mse = 0.0f;     // plain MSE tile (l=0 group, s=0 blocks: never fast)
    const bool own_mse = (s == 0) && (q == 0);
    // every element of this thread's 16x4 tile clamped <=> min s-index >= 511
    const bool fully = (4 * j + L0) >= (TT - 1);

    if (__all(fully)) {
        // FAST PATH (wave-uniform): all reads would hit g[511].
        float rsum = 0.0f;
        #pragma unroll
        for (int o = 0; o < 16; ++o) rsum += r[o];
        const float d0 = p.x - g511, d1 = p.y - g511,
                    d2 = p.z - g511, d3 = p.w - g511;
        acc = rsum * (d0 * d0 + d1 * d1 + d2 * d2 + d3 * d3);
    } else {
        // SLOW PATH: 20-float window, float4 indices base4..base4+4 (max 255)
        const int base4 = j + (L0 >> 2);
        float4 w4[5];
        #pragma unroll
        for (int k = 0; k < 5; ++k) w4[k] = s_ext4[base4 + k];
        const float* w = reinterpret_cast<const float*>(w4);

        #pragma unroll
        for (int k = 0; k < 4; ++k) {
            #pragma unroll
            for (int bb = 0; bb < 4; ++bb) {
                const int o = 4 * k + bb;
                const float d0 = p.x - w[o + 0];
                const float d1 = p.y - w[o + 1];
                const float d2 = p.z - w[o + 2];
                const float d3 = p.w - w[o + 3];
                const float sb = d0 * d0 + d1 * d1 + d2 * d2 + d3 * d3;
                acc = fmaf(r[o], sb, acc);
                if (k == 0 && bb == 0 && own_mse) mse = sb;   // l=0 tile IS the MSE
            }
        }
    }

    // total = (mse + 0.5*lag) * w, mean scale 1/(B*T) = 1/65536 exact
    float v = fmaf(LAG_PENALTY, acc, mse) * wts[row] * (1.0f / (float)(BB * TT));

    // wave64 shuffle reduction -> per-block partial (plain store, no atomic)
    for (int off = 32; off > 0; off >>= 1)
        v += __shfl_down(v, off, 64);

    const int wave = tid >> 6;
    if ((tid & 63) == 0) s_part[wave] = v;
    __syncthreads();

    if (tid == 0) {
        float sum = 0.0f;
        #pragma unroll
        for (int i = 0; i < 8; ++i) sum += s_part[i];
        part[bid] = sum;             // overwritten every call
    }
}

__global__ __launch_bounds__(1024) void WeightedLagDenseLoss_reduce(
    const float* __restrict__ part,
    float* __restrict__ out)
{
    __shared__ float s_part[16];
    const int t = threadIdx.x;

    float v = part[t];               // NPART == 1024 == blockDim.x

    for (int off = 32; off > 0; off >>= 1)
        v += __shfl_down(v, off, 64);

    const int wave = t >> 6;
    if ((t & 63) == 0) s_part[wave] = v;
    __syncthreads();

    if (t == 0) {
        float sum = 0.0f;
        #pragma unroll
        for (int i = 0; i < 16; ++i) sum += s_part[i];
        out[0] = sum;                // overwrite, no zero-init needed
    }
}

extern "C" void kernel_launch(void* const* d_in, const int* in_sizes, int n_in,
                              void* d_out, int out_size, void* d_ws, size_t ws_size,
                              hipStream_t stream) {
    const float* pred = (const float*)d_in[0];
    const float* tgt  = (const float*)d_in[1];
    const float* wts  = (const float*)d_in[2];
    float* out  = (float*)d_out;
    float* part = (float*)d_ws;      // 1024 floats = 4 KB scratch

    WeightedLagDenseLoss_main<<<dim3(NPART), dim3(TT), 0, stream>>>(pred, tgt, wts, part);
    WeightedLagDenseLoss_reduce<<<dim3(1), dim3(NPART), 0, stream>>>(part, out);
}